// Round 2
// baseline (183.148 us; speedup 1.0000x reference)
//
#include <hip/hip_runtime.h>

// Fastfood transform, LL = 2^23, d = 1024.
// out = FWHT_LL( GG * (FWHT_LL(BB .* pad(x)))[Pi] )
// Key identity: FWHT_LL of a vector supported on [0,1024) is w[i & 1023]
// with w = FWHT_1024(BB[:1024] * x). So stage 1 is a 1024-point FWHT.

#define LL_LOG 23
#define LOW_LOG 14              // bits done in contiguous-chunk kernel
#define HIGH_LOG 9              // bits done in strided kernel (LL_LOG - LOW_LOG)
#define CHUNK (1 << LOW_LOG)    // 16384 floats = 64 KB LDS
#define NROWS (1 << HIGH_LOG)   // 512
#define NCOLS (1 << LOW_LOG)    // 16384 columns for the high-stage view

// ---------------- Kernel 1: w = FWHT_1024(BB[:1024] * x) ----------------
__global__ __launch_bounds__(256) void k_small_fwht(
    const float* __restrict__ x, const float* __restrict__ BB,
    float* __restrict__ w)
{
    __shared__ float s[1024];
    const int tid = threadIdx.x;
    for (int k = 0; k < 4; ++k) {
        int i = k * 256 + tid;
        s[i] = BB[i] * x[i];
    }
    __syncthreads();
    for (int st = 0; st < 10; ++st) {
        const int h = 1 << st;
        for (int k = 0; k < 2; ++k) {
            int j = k * 256 + tid;                 // butterfly index 0..511
            int i = ((j >> st) << (st + 1)) | (j & (h - 1));
            float a = s[i], b = s[i + h];
            s[i] = a + b;
            s[i + h] = a - b;
        }
        __syncthreads();
    }
    for (int k = 0; k < 4; ++k) {
        int i = k * 256 + tid;
        w[i] = s[i];
    }
}

// ---- Kernel 2: gather/scale + FWHT over low 14 bits (contiguous chunks) ----
__global__ __launch_bounds__(256) void k_low(
    const int* __restrict__ Pi, const float* __restrict__ GG,
    const float* __restrict__ w, float* __restrict__ out)
{
    extern __shared__ float s[];                   // CHUNK floats = 64 KB
    const int tid = threadIdx.x;
    const long base = (long)blockIdx.x * CHUNK;    // element base of this chunk

    // load (vectorized 16B/lane): mul_4[i] = w[Pi[i] & 1023] * GG[i]
    {
        const int4*   Pi4 = (const int4*)(Pi + base);
        const float4* GG4 = (const float4*)(GG + base);
        float4*       s4  = (float4*)s;
        for (int k = 0; k < CHUNK / 1024; ++k) {   // 16 iters
            int v = k * 256 + tid;                 // vec4 index within chunk
            int4   p = Pi4[v];
            float4 g = GG4[v];
            float4 r;
            r.x = w[p.x & 1023] * g.x;
            r.y = w[p.y & 1023] * g.y;
            r.z = w[p.z & 1023] * g.z;
            r.w = w[p.w & 1023] * g.w;
            s4[v] = r;
        }
    }
    __syncthreads();

    for (int st = 0; st < LOW_LOG; ++st) {
        const int h = 1 << st;
        for (int k = 0; k < CHUNK / 512; ++k) {    // 8192 butterflies / 256 thr
            int j = k * 256 + tid;
            int i = ((j >> st) << (st + 1)) | (j & (h - 1));
            float a = s[i], b = s[i + h];
            s[i] = a + b;
            s[i + h] = a - b;
        }
        __syncthreads();
    }

    // store (vectorized 16B/lane)
    {
        float4*       o4 = (float4*)(out + base);
        const float4* s4 = (const float4*)s;
        for (int k = 0; k < CHUNK / 1024; ++k) {
            int v = k * 256 + tid;
            o4[v] = s4[v];
        }
    }
}

// ---- Kernel 3: FWHT over high 9 bits (stride 2^14), in-place on out ----
// View out as [NROWS=512][NCOLS=16384]; butterfly along rows per column.
// Each block owns 32 consecutive columns for all 512 rows (64 KB LDS tile).
__global__ __launch_bounds__(256) void k_high(float* __restrict__ out)
{
    extern __shared__ float s[];                   // [512][32] floats = 64 KB
    const int tid = threadIdx.x;
    const int t = tid & 31;                        // column within tile
    const int g = tid >> 5;                        // 0..7 row group
    const long lo_base = (long)blockIdx.x * 32;

    for (int k = 0; k < NROWS / 8; ++k) {
        int hi = k * 8 + g;
        s[hi * 32 + t] = out[(long)hi * NCOLS + lo_base + t];
    }
    __syncthreads();

    for (int st = 0; st < HIGH_LOG; ++st) {
        const int h = 1 << st;
        for (int k = 0; k < (NROWS / 2) / 8; ++k) { // 256 bfly/col, 8 groups
            int j = g * 32 + k;                     // 0..255
            int i = ((j >> st) << (st + 1)) | (j & (h - 1));
            float a = s[i * 32 + t], b = s[(i + h) * 32 + t];
            s[i * 32 + t] = a + b;
            s[(i + h) * 32 + t] = a - b;
        }
        __syncthreads();
    }

    for (int k = 0; k < NROWS / 8; ++k) {
        int hi = k * 8 + g;
        out[(long)hi * NCOLS + lo_base + t] = s[hi * 32 + t];
    }
}

extern "C" void kernel_launch(void* const* d_in, const int* in_sizes, int n_in,
                              void* d_out, int out_size, void* d_ws, size_t ws_size,
                              hipStream_t stream) {
    const float* x  = (const float*)d_in[0];   // (1024,) f32
    const float* BB = (const float*)d_in[1];   // (LL,)   f32, only [:1024] used
    const float* GG = (const float*)d_in[2];   // (LL,)   f32
    const int*   Pi = (const int*)  d_in[3];   // (LL,)   i32 permutation
    float* out = (float*)d_out;                // (LL,)   f32
    float* w   = (float*)d_ws;                 // 1024 f32 scratch

    k_small_fwht<<<1, 256, 0, stream>>>(x, BB, w);

    const int nchunks = (1 << LL_LOG) / CHUNK;         // 512
    k_low<<<nchunks, 256, CHUNK * sizeof(float), stream>>>(Pi, GG, w, out);

    const int ntiles = NCOLS / 32;                     // 512
    k_high<<<ntiles, 256, NROWS * 32 * sizeof(float), stream>>>(out);
}

// Round 3
// 139.421 us; speedup vs baseline: 1.3136x; 1.3136x over previous
//
#include <hip/hip_runtime.h>

// Fastfood transform, LL = 2^23, d = 1024.
// out = FWHT_LL( GG * (FWHT_LL(BB .* pad(x)))[Pi] )
// Identity: FWHT_LL of a vector supported on [0,1024) is w[i & 1023],
// w = FWHT_1024(BB[:1024] * x)  -> computed redundantly per block in LDS.
//
// Second FWHT split: bits 0..13 inside 16384-element chunks (k_low),
// bits 14..22 across chunks (k_high). Both kernels keep data in REGISTERS
// (64 floats/thread): 6 reg stages + (2 shuffle stages) + LDS transpose +
// remaining reg stages. LDS transpose uses a 32x260-padded tile, 2 rounds,
// bank-conflict-free reads/writes (verified by hand: every access 2-way max).

#define LOWC 16384
#define NC   16384
#define TRPAD 260              // 32 rows * 260 floats = 33280 B

__device__ __forceinline__ void fwht64(float* v) {
  #pragma unroll
  for (int s = 0; s < 6; ++s) {
    const int d = 1 << s;
    #pragma unroll
    for (int jj = 0; jj < 64; ++jj) {
      if ((jj & d) == 0) {
        float a = v[jj], b = v[jj + d];
        v[jj]     = a + b;
        v[jj + d] = a - b;
      }
    }
  }
}

// ---------------- k_low: gather/scale + FWHT over bits 0..13 ----------------
// Ownership A: i = (t>>2)<<8 | (j>>2)<<4 | (t&3)<<2 | (j&3)
//   -> in-register i-bits {0,1,4,5,6,7} (fwht64), shuffle i-bits {2,3} (lane
//      bits 0,1), vec4 global loads at 64B granularity.
// Ownership B: i = j2*256 + t2 -> in-register i-bits {8..13}, perfectly
//   coalesced scalar stores.
__global__ __launch_bounds__(256) void k_low(
    const float* __restrict__ x, const float* __restrict__ BB,
    const int* __restrict__ Pi, const float* __restrict__ GG,
    float* __restrict__ out)
{
  __shared__ float w[1024];
  __shared__ float tr[32 * TRPAD];
  const int t = threadIdx.x;
  const long base = (long)blockIdx.x * LOWC;

  // ---- w = FWHT_1024(BB[:1024] * x), redundantly per block ----
  {
    float4 xx = ((const float4*)x)[t];
    float4 bb = ((const float4*)BB)[t];
    float a0 = xx.x * bb.x, a1 = xx.y * bb.y, a2 = xx.z * bb.z, a3 = xx.w * bb.w;
    float b0 = a0 + a1, b1 = a0 - a1, b2 = a2 + a3, b3 = a2 - a3;
    w[4 * t + 0] = b0 + b2; w[4 * t + 1] = b1 + b3;
    w[4 * t + 2] = b0 - b2; w[4 * t + 3] = b1 - b3;
  }
  __syncthreads();
  #pragma unroll
  for (int s = 2; s <= 9; ++s) {
    const int h = 1 << s;
    #pragma unroll
    for (int k2 = 0; k2 < 2; ++k2) {
      int jb = k2 * 256 + t;                       // 0..511 butterflies
      int i0 = ((jb >> s) << (s + 1)) | (jb & (h - 1));
      float aa = w[i0], bv = w[i0 + h];
      w[i0] = aa + bv; w[i0 + h] = aa - bv;
    }
    __syncthreads();
  }

  // ---- gather + scale into registers (ownership A) ----
  float v[64];
  {
    const int4*   Pi4 = (const int4*)(Pi + base);
    const float4* GG4 = (const float4*)(GG + base);
    const int vbase = (t >> 2) * 64 + (t & 3);
    #pragma unroll
    for (int q = 0; q < 16; ++q) {
      int4   p = Pi4[vbase + q * 4];
      float4 g = GG4[vbase + q * 4];
      v[4 * q + 0] = w[p.x & 1023] * g.x;
      v[4 * q + 1] = w[p.y & 1023] * g.y;
      v[4 * q + 2] = w[p.z & 1023] * g.z;
      v[4 * q + 3] = w[p.w & 1023] * g.w;
    }
  }

  // ---- phase A: 6 register stages (i bits 0,1,4,5,6,7) ----
  fwht64(v);

  // ---- shuffle stages: i bits 2,3 == lane bits 0,1 ----
  #pragma unroll
  for (int jj = 0; jj < 64; ++jj) {
    float u = __shfl_xor(v[jj], 1);
    v[jj] = (t & 1) ? (u - v[jj]) : (v[jj] + u);
  }
  #pragma unroll
  for (int jj = 0; jj < 64; ++jj) {
    float u = __shfl_xor(v[jj], 2);
    v[jj] = (t & 2) ? (u - v[jj]) : (v[jj] + u);
  }

  // ---- LDS transpose to ownership B (2 rounds over old-j halves) ----
  // value (t, j) -> new owner t2 = (j>>2)<<4 | (t&3)<<2 | (j&3), reg j2 = t>>2
  float nv[64];
  #pragma unroll
  for (int r = 0; r < 2; ++r) {
    if (r == 1) __syncthreads();                   // protect tr reuse
    #pragma unroll
    for (int jl = 0; jl < 32; ++jl)
      tr[jl * TRPAD + t] = v[r * 32 + jl];
    __syncthreads();
    if ((t >> 7) == r) {                           // wave-uniform branch
      const int jl = (((t >> 4) << 2) | (t & 3)) & 31;  // old-j - 32r
      const int cc = (t >> 2) & 3;
      #pragma unroll
      for (int j2 = 0; j2 < 64; ++j2)
        nv[j2] = tr[jl * TRPAD + j2 * 4 + cc];
    }
  }

  // ---- phase B: 6 register stages (i bits 8..13) ----
  fwht64(nv);

  // ---- store, perfectly coalesced: i = j2*256 + t ----
  #pragma unroll
  for (int j2 = 0; j2 < 64; ++j2)
    out[base + (long)j2 * 256 + t] = nv[j2];
}

// ---------------- k_high: FWHT over bits 14..22, in-place ----------------
// View out as [512 rows][16384 cols]; block owns 32 cols x all 512 rows.
// Ownership A: row = j*8 + (t>>5), col = cb + (t&31) -> reg stages row-bits 3..8
// Ownership B: row = (t>>5)*64 + j2               -> reg stages row-bits 0..2
__global__ __launch_bounds__(256) void k_high(float* __restrict__ out)
{
  __shared__ float tr[32 * TRPAD];
  const int t = threadIdx.x;
  const long cb = (long)blockIdx.x * 32;
  const int c = t & 31;
  const int g = t >> 5;

  float v[64];
  #pragma unroll
  for (int j = 0; j < 64; ++j)
    v[j] = out[(long)(j * 8 + g) * NC + cb + c];

  fwht64(v);                                       // row bits 3..8

  float nv[64];
  #pragma unroll
  for (int r = 0; r < 2; ++r) {
    if (r == 1) __syncthreads();
    #pragma unroll
    for (int jl = 0; jl < 32; ++jl)
      tr[jl * TRPAD + t] = v[r * 32 + jl];
    __syncthreads();
    if ((t >> 7) == r) {
      #pragma unroll
      for (int j2 = 0; j2 < 64; ++j2) {
        int jl = ((g & 3) * 8) + (j2 >> 3);        // old-j - 32r
        nv[j2] = tr[jl * TRPAD + ((j2 & 7) << 5) + c];
      }
    }
  }

  // row bits 0..2: FWHT_8 within each 8-group of j2
  #pragma unroll
  for (int s = 0; s < 3; ++s) {
    const int d = 1 << s;
    #pragma unroll
    for (int jj = 0; jj < 64; ++jj) {
      if ((jj & d) == 0) {
        float a = nv[jj], b = nv[jj + d];
        nv[jj]     = a + b;
        nv[jj + d] = a - b;
      }
    }
  }

  #pragma unroll
  for (int j2 = 0; j2 < 64; ++j2)
    out[(long)(g * 64 + j2) * NC + cb + c] = nv[j2];
}

extern "C" void kernel_launch(void* const* d_in, const int* in_sizes, int n_in,
                              void* d_out, int out_size, void* d_ws, size_t ws_size,
                              hipStream_t stream) {
  const float* x  = (const float*)d_in[0];   // (1024,) f32
  const float* BB = (const float*)d_in[1];   // (LL,)   f32, only [:1024] used
  const float* GG = (const float*)d_in[2];   // (LL,)   f32
  const int*   Pi = (const int*)  d_in[3];   // (LL,)   i32 permutation
  float* out = (float*)d_out;                // (LL,)   f32

  const int nchunks = (1 << 23) / LOWC;      // 512
  k_low<<<nchunks, 256, 0, stream>>>(x, BB, Pi, GG, out);

  const int ntiles = NC / 32;                // 512
  k_high<<<ntiles, 256, 0, stream>>>(out);
}

// Round 6
// 136.471 us; speedup vs baseline: 1.3420x; 1.0216x over previous
//
#include <hip/hip_runtime.h>
#include <hip/hip_bf16.h>

// Fastfood transform, LL = 2^23, d = 1024.
// out = FWHT_LL( GG * (FWHT_LL(BB .* pad(x)))[Pi] )
// FWHT_LL of a vector supported on [0,1024) is w[i & 1023],
// w = FWHT_1024(BB[:1024] * x)  (recomputed per block, 4 KB LDS).
// Second FWHT: bits 0..13 in-chunk (k_low), bits 14..22 cross-chunk
// (k_high). bf16 intermediate in d_ws halves mid traffic. All butterflies
// in registers; one padded-LDS transpose per kernel (conflict-free).
// NOTE (R5): hipLaunchCooperativeKernel does NOT survive graph capture in
// this harness -> grid sync must be a kernel boundary. Two plain launches.

#define NC 16384
#define TRPAD 260              // 32 rows * 260 floats, conflict-free transpose

__device__ __forceinline__ void fwht64(float* v) {
  #pragma unroll
  for (int s = 0; s < 6; ++s) {
    const int d = 1 << s;
    #pragma unroll
    for (int jj = 0; jj < 64; ++jj) {
      if ((jj & d) == 0) {
        float a = v[jj], b = v[jj + d];
        v[jj]     = a + b;
        v[jj + d] = a - b;
      }
    }
  }
}

// ---------------- k_low: gather/scale + FWHT over bits 0..13 ----------------
__global__ __launch_bounds__(256) void k_low(
    const float* __restrict__ x, const float* __restrict__ BB,
    const int* __restrict__ Pi, const float* __restrict__ GG,
    __hip_bfloat16* __restrict__ mid)
{
  __shared__ float w[1024];
  __shared__ float tr[32 * TRPAD];
  const int t = threadIdx.x;
  const long base = (long)blockIdx.x * NC;

  // Ownership A: i = (t>>2)<<8 | q<<4 | (t&3)<<2 | e   [j = 4q+e]
  const int4*   Pi4 = (const int4*)(Pi + base);
  const float4* GG4 = (const float4*)(GG + base);
  const int vb = (t >> 2) * 64 + (t & 3);

  // hoist Pi loads: HBM latency hides under the w-prologue below
  int4 p[16];
  #pragma unroll
  for (int q = 0; q < 16; ++q) p[q] = Pi4[vb + 4 * q];

  // ---- w = FWHT_1024(BB[:1024] * x) ----
  {
    float4 xx = ((const float4*)x)[t];
    float4 bb = ((const float4*)BB)[t];
    float a0 = xx.x * bb.x, a1 = xx.y * bb.y, a2 = xx.z * bb.z, a3 = xx.w * bb.w;
    float b0 = a0 + a1, b1 = a0 - a1, b2 = a2 + a3, b3 = a2 - a3;
    w[4 * t + 0] = b0 + b2; w[4 * t + 1] = b1 + b3;
    w[4 * t + 2] = b0 - b2; w[4 * t + 3] = b1 - b3;
  }
  __syncthreads();
  #pragma unroll
  for (int s = 2; s <= 9; ++s) {
    const int h = 1 << s;
    #pragma unroll
    for (int k2 = 0; k2 < 2; ++k2) {
      int jb = k2 * 256 + t;
      int i0 = ((jb >> s) << (s + 1)) | (jb & (h - 1));
      float aa = w[i0], bv = w[i0 + h];
      w[i0] = aa + bv; w[i0 + h] = aa - bv;
    }
    __syncthreads();
  }

  // ---- gather + scale ----
  float v[64];
  #pragma unroll
  for (int q = 0; q < 16; ++q) {
    float4 g = GG4[vb + 4 * q];
    v[4 * q + 0] = w[p[q].x & 1023] * g.x;
    v[4 * q + 1] = w[p[q].y & 1023] * g.y;
    v[4 * q + 2] = w[p[q].z & 1023] * g.z;
    v[4 * q + 3] = w[p[q].w & 1023] * g.w;
  }

  fwht64(v);                                       // i bits 0,1,4,5,6,7

  #pragma unroll
  for (int jj = 0; jj < 64; ++jj) {                // i bit 2 (lane bit 0)
    float u = __shfl_xor(v[jj], 1);
    v[jj] = (t & 1) ? (u - v[jj]) : (v[jj] + u);
  }
  #pragma unroll
  for (int jj = 0; jj < 64; ++jj) {                // i bit 3 (lane bit 1)
    float u = __shfl_xor(v[jj], 2);
    v[jj] = (t & 2) ? (u - v[jj]) : (v[jj] + u);
  }

  // ---- LDS transpose to ownership B: i = j2*256 + t ----
  float nv[64];
  #pragma unroll
  for (int r = 0; r < 2; ++r) {
    if (r == 1) __syncthreads();
    #pragma unroll
    for (int jl = 0; jl < 32; ++jl)
      tr[jl * TRPAD + t] = v[r * 32 + jl];
    __syncthreads();
    if ((t >> 7) == r) {                           // wave-uniform
      const int jl = (((t >> 4) << 2) | (t & 3)) & 31;
      const int cc = (t >> 2) & 3;
      #pragma unroll
      for (int j2 = 0; j2 < 64; ++j2)
        nv[j2] = tr[jl * TRPAD + j2 * 4 + cc];
    }
  }

  fwht64(nv);                                      // i bits 8..13

  #pragma unroll
  for (int j2 = 0; j2 < 64; ++j2)                  // coalesced bf16 stores
    mid[base + j2 * 256 + t] = __float2bfloat16(nv[j2]);
}

// ---------------- k_high: FWHT over bits 14..22 ----------------
// View mid as [512 rows][16384 cols]; block owns 32 cols x all 512 rows.
__global__ __launch_bounds__(256) void k_high(
    const __hip_bfloat16* __restrict__ mid, float* __restrict__ out)
{
  __shared__ float tr[32 * TRPAD];
  const int t = threadIdx.x;
  const long cb = (long)blockIdx.x * 32;
  const int c = t & 31;
  const int g2 = t >> 5;

  float v[64];
  #pragma unroll
  for (int j = 0; j < 64; ++j)
    v[j] = __bfloat162float(mid[(long)(j * 8 + g2) * NC + cb + c]);

  fwht64(v);                                       // row bits 3..8

  float nv[64];
  #pragma unroll
  for (int r = 0; r < 2; ++r) {
    if (r == 1) __syncthreads();
    #pragma unroll
    for (int jl = 0; jl < 32; ++jl)
      tr[jl * TRPAD + t] = v[r * 32 + jl];
    __syncthreads();
    if ((t >> 7) == r) {
      #pragma unroll
      for (int j2 = 0; j2 < 64; ++j2) {
        int jl = ((g2 & 3) * 8) + (j2 >> 3);
        nv[j2] = tr[jl * TRPAD + ((j2 & 7) << 5) + c];
      }
    }
  }

  #pragma unroll
  for (int s = 0; s < 3; ++s) {                    // row bits 0..2
    const int d = 1 << s;
    #pragma unroll
    for (int jj = 0; jj < 64; ++jj) {
      if ((jj & d) == 0) {
        float a = nv[jj], b = nv[jj + d];
        nv[jj]     = a + b;
        nv[jj + d] = a - b;
      }
    }
  }

  #pragma unroll
  for (int j2 = 0; j2 < 64; ++j2)
    out[(long)(g2 * 64 + j2) * NC + cb + c] = nv[j2];
}

extern "C" void kernel_launch(void* const* d_in, const int* in_sizes, int n_in,
                              void* d_out, int out_size, void* d_ws, size_t ws_size,
                              hipStream_t stream) {
  const float* x  = (const float*)d_in[0];   // (1024,) f32
  const float* BB = (const float*)d_in[1];   // (LL,)   f32, only [:1024] used
  const float* GG = (const float*)d_in[2];   // (LL,)   f32
  const int*   Pi = (const int*)  d_in[3];   // (LL,)   i32 permutation
  float* out = (float*)d_out;                // (LL,)   f32
  __hip_bfloat16* mid = (__hip_bfloat16*)d_ws;  // 16 MB bf16 intermediate

  k_low<<<512, 256, 0, stream>>>(x, BB, Pi, GG, mid);
  k_high<<<512, 256, 0, stream>>>(mid, out);
}